// Round 1
// baseline (150.422 us; speedup 1.0000x reference)
//
#include <hip/hip_runtime.h>
#include <hip/hip_bf16.h>
#include <math.h>

#define NB 2
#define NN 4096
#define FIN 128
#define FOUT 64
#define LALPHA 0.2f

// ws float-offsets
#define WS_S1   0                          // NB*NN floats
#define WS_S2   (NB*NN)                    // NB*NN floats
#define WS_WHT  (2*NB*NN)                  // NB*FOUT*NN ushorts = NB*FOUT*NN/2 floats

typedef __attribute__((ext_vector_type(8))) short short8;
typedef __attribute__((ext_vector_type(4))) float f32x4;

static __device__ inline unsigned int pack2bf(float x, float y) {
    float2 f2; f2.x = x; f2.y = y;
    __hip_bfloat162 pp = __float22bfloat162_rn(f2);
    return *reinterpret_cast<unsigned int*>(&pp);
}

// K1: Wh = h@W ; s1 = Wh@a1 ; s2 = Wh@a2 ; WhT bf16 [b][f][j].
// One wave per (b,row); lane = out feature. Block = 4 waves = 4 consecutive rows.
__global__ __launch_bounds__(256) void k1_proj(const float* __restrict__ h,
                                               const float* __restrict__ W,
                                               const float* __restrict__ a,
                                               float* __restrict__ ws) {
    __shared__ float tbuf[4][68];
    int gid  = blockIdx.x * 256 + threadIdx.x;
    int wid  = gid >> 6;            // 0 .. NB*NN-1
    int lane = threadIdx.x & 63;
    int w    = threadIdx.x >> 6;
    const float* hrow = h + (size_t)wid * FIN;
    float h0 = hrow[lane];
    float h1 = hrow[64 + lane];
    float acc = 0.f;
#pragma unroll
    for (int f = 0; f < 64; ++f) {
        float hf = __shfl(h0, f);
        acc = fmaf(hf, W[f * FOUT + lane], acc);
    }
#pragma unroll
    for (int f = 0; f < 64; ++f) {
        float hf = __shfl(h1, f);
        acc = fmaf(hf, W[(64 + f) * FOUT + lane], acc);
    }
    tbuf[w][lane] = acc;
    float v1 = acc * a[lane];
    float v2 = acc * a[FOUT + lane];
#pragma unroll
    for (int off = 32; off; off >>= 1) {
        v1 += __shfl_xor(v1, off);
        v2 += __shfl_xor(v2, off);
    }
    if (lane == 0) {
        ws[WS_S1 + wid] = v1;
        ws[WS_S2 + wid] = v2;
    }
    __syncthreads();
    // transpose 4 rows x 64 f -> WhT bf16 [b][f][n0..n0+3]
    if (threadIdx.x < 64) {
        int f = threadIdx.x;
        int wid0 = blockIdx.x * 4;
        int b  = wid0 >> 12;         // wid0 / NN
        int n0 = wid0 & (NN - 1);
        unsigned short* whT = (unsigned short*)(ws + WS_WHT);
        uint2 pk;
        pk.x = pack2bf(tbuf[0][f], tbuf[1][f]);
        pk.y = pack2bf(tbuf[2][f], tbuf[3][f]);
        *(uint2*)&whT[(size_t)(b * FOUT + f) * NN + n0] = pk;
    }
}

// K3: fused masked softmax + P@Wh via MFMA + in-block 16-wave reduction +
// softmax-divide + ELU -> final output. No HBM partial slab, no k4.
// Block = 1024 threads = 16 waves; block handles one 16-row tile x all 4096 j.
// Wave w covers j in [w*256, (w+1)*256). Main loop identical to the verified
// slab version; only the epilogue changed (LDS reduce instead of HBM slab).
// grid = 256 blocks = 1 block/CU (130 KiB LDS), 16 waves/CU = 4/SIMD.
__global__ __launch_bounds__(1024, 4) void k3_attn(const int* __restrict__ adj,
                                                   const float* __restrict__ ws,
                                                   float* __restrict__ out) {
    __shared__ float red[16][2048];   // 128 KiB: per-wave D-tile partials
    __shared__ float lred[16][32];    // 2 KiB: per-wave l partials (b*16+row)
    const int tid  = threadIdx.x;
    const int w    = tid >> 6;                   // wave id = j-chunk 0..15
    const int lane = tid & 63;
    const int col  = lane & 15;
    const int quad = lane >> 4;
    const int rt   = blockIdx.x;                 // row-tile 0..255
    const int i0   = rt * 16;
    const int jbase = w * 256;

    const float* __restrict__ s1 = ws + WS_S1;
    const float* __restrict__ s2 = ws + WS_S2;
    const unsigned short* __restrict__ whT = (const unsigned short*)(ws + WS_WHT);

    float s1a[2];
#pragma unroll
    for (int b = 0; b < 2; ++b) s1a[b] = s1[b * NN + i0 + col];

    f32x4 acc[2][4];        // [batch][nt]
    float lsum[2] = {0.f, 0.f};
#pragma unroll
    for (int b = 0; b < 2; ++b)
#pragma unroll
        for (int nt = 0; nt < 4; ++nt) acc[b][nt] = (f32x4)0.f;

#pragma unroll
    for (int ks = 0; ks < 8; ++ks) {
        const int j8 = jbase + ks * 32 + quad * 8;   // this lane's 8-j base
        int4 ava = *(const int4*)&adj[(size_t)(i0 + col) * NN + j8];
        int4 avb = *(const int4*)&adj[(size_t)(i0 + col) * NN + j8 + 4];
        int am[8] = {ava.x, ava.y, ava.z, ava.w, avb.x, avb.y, avb.z, avb.w};
#pragma unroll
        for (int b = 0; b < 2; ++b) {
            float4 s2lo = *(const float4*)&s2[b * NN + j8];
            float4 s2hi = *(const float4*)&s2[b * NN + j8 + 4];
            float sj[8] = {s2lo.x, s2lo.y, s2lo.z, s2lo.w,
                           s2hi.x, s2hi.y, s2hi.z, s2hi.w};
            float p[8];
#pragma unroll
            for (int jj = 0; jj < 8; ++jj) {
                float e = s1a[b] + sj[jj];
                e = fmaxf(e, LALPHA * e);          // leakyrelu
                float pe = __expf(e);
                p[jj] = am[jj] > 0 ? pe : 0.f;     // mask
                lsum[b] += p[jj];
            }
            unsigned int pk[4];
#pragma unroll
            for (int q = 0; q < 4; ++q) pk[q] = pack2bf(p[2 * q], p[2 * q + 1]);
            short8 afrag = *(short8*)pk;
#pragma unroll
            for (int nt = 0; nt < 4; ++nt) {
                short8 bfrag = *(const short8*)
                    &whT[(size_t)(b * FOUT + nt * 16 + col) * NN + j8];
                acc[b][nt] = __builtin_amdgcn_mfma_f32_16x16x32_bf16(
                    afrag, bfrag, acc[b][nt], 0, 0, 0);
            }
        }
    }

    // ---- epilogue: LDS partials, 16-way in-block reduce, finalize ----
#pragma unroll
    for (int b = 0; b < 2; ++b) {
        // l: sum over quads -> row (=col) total for this wave's j-chunk
        float v = lsum[b];
        v += __shfl_xor(v, 16);
        v += __shfl_xor(v, 32);
        if (quad == 0) lred[w][b * 16 + col] = v;
#pragma unroll
        for (int nt = 0; nt < 4; ++nt)
#pragma unroll
            for (int reg = 0; reg < 4; ++reg)
                red[w][(((b * 4 + nt) * 4 + reg) << 6) + lane] = acc[b][nt][reg];
    }
    __syncthreads();

    // 2048 outputs per block, 1024 threads -> 2 each. Same (lane,reg) mapping
    // the old k4 used, but sourced from LDS.
#pragma unroll
    for (int e = 0; e < 2; ++e) {
        int flat = e * 1024 + tid;                // b*1024 + r16*64 + f
        int f    = flat & 63;
        int r16  = (flat >> 6) & 15;
        int b    = flat >> 10;
        int q2   = r16 >> 2, reg = r16 & 3;
        int c2   = f & 15,   nt  = f >> 4;
        int ln   = q2 * 16 + c2;
        int off  = (((b * 4 + nt) * 4 + reg) << 6) + ln;
        float acv = 0.f, l = 0.f;
#pragma unroll
        for (int ww = 0; ww < 16; ++ww) {
            acv += red[ww][off];
            l   += lred[ww][b * 16 + r16];
        }
        float v = acv / l;
        out[(size_t)(((b * NN) + i0 + r16) << 6) + f] = v > 0.f ? v : (__expf(v) - 1.f);
    }
}

extern "C" void kernel_launch(void* const* d_in, const int* in_sizes, int n_in,
                              void* d_out, int out_size, void* d_ws, size_t ws_size,
                              hipStream_t stream) {
    const float* h   = (const float*)d_in[0];
    const int*   adj = (const int*)d_in[1];
    const float* W   = (const float*)d_in[2];
    const float* a   = (const float*)d_in[3];
    float* ws  = (float*)d_ws;
    float* out = (float*)d_out;

    hipLaunchKernelGGL(k1_proj, dim3(NB * NN / 4), dim3(256), 0, stream, h, W, a, ws);
    hipLaunchKernelGGL(k3_attn, dim3(256), dim3(1024), 0, stream, adj, ws, out);
}

// Round 2
// 149.984 us; speedup vs baseline: 1.0029x; 1.0029x over previous
//
#include <hip/hip_runtime.h>
#include <hip/hip_bf16.h>
#include <math.h>

#define NB 2
#define NN 4096
#define FIN 128
#define FOUT 64
#define LALPHA 0.2f

// ws float-offsets
#define WS_S1    0                          // NB*NN floats
#define WS_S2    (NB*NN)                    // NB*NN floats
#define WS_WHT   (2*NB*NN)                  // NB*FOUT*NN ushorts = NB*FOUT*NN/2 floats
#define WS_ABITS (WS_WHT + NB*FOUT*NN/2)    // NN*(NN/32) uint32 = 2 MiB

typedef __attribute__((ext_vector_type(8))) short short8;
typedef __attribute__((ext_vector_type(4))) float f32x4;

static __device__ inline unsigned int pack2bf(float x, float y) {
    float2 f2; f2.x = x; f2.y = y;
    __hip_bfloat162 pp = __float22bfloat162_rn(f2);
    return *reinterpret_cast<unsigned int*>(&pp);
}

// K1: Wh = h@W ; s1 = Wh@a1 ; s2 = Wh@a2 ; WhT bf16 [b][f][j].
// One wave per (b,row); lane = out feature. Block = 4 waves = 4 consecutive rows.
// ALSO: packs 2 rows of adj into the 2 MiB bitmask (independent streaming work
// that overlaps the shfl/fma latency chain of the projection).
__global__ __launch_bounds__(256) void k1_proj(const float* __restrict__ h,
                                               const float* __restrict__ W,
                                               const float* __restrict__ a,
                                               const int* __restrict__ adj,
                                               float* __restrict__ ws) {
    __shared__ float tbuf[4][68];
    int gid  = blockIdx.x * 256 + threadIdx.x;
    int wid  = gid >> 6;            // 0 .. NB*NN-1
    int lane = threadIdx.x & 63;
    int w    = threadIdx.x >> 6;

    // ---- adj pack: issue loads early (independent of proj chain) ----
    // block packs rows 2*bid, 2*bid+1 ; thread t -> row 2*bid + (t>>7), word t&127
    int prow  = 2 * blockIdx.x + (threadIdx.x >> 7);
    int pword = threadIdx.x & 127;
    const int4* psrc = (const int4*)&adj[(size_t)prow * NN + pword * 32];
    int4 pv[8];
#pragma unroll
    for (int k = 0; k < 8; ++k) pv[k] = psrc[k];

    // ---- projection ----
    const float* hrow = h + (size_t)wid * FIN;
    float h0 = hrow[lane];
    float h1 = hrow[64 + lane];
    float acc = 0.f;
#pragma unroll
    for (int f = 0; f < 64; ++f) {
        float hf = __shfl(h0, f);
        acc = fmaf(hf, W[f * FOUT + lane], acc);
    }
#pragma unroll
    for (int f = 0; f < 64; ++f) {
        float hf = __shfl(h1, f);
        acc = fmaf(hf, W[(64 + f) * FOUT + lane], acc);
    }
    tbuf[w][lane] = acc;
    float v1 = acc * a[lane];
    float v2 = acc * a[FOUT + lane];
#pragma unroll
    for (int off = 32; off; off >>= 1) {
        v1 += __shfl_xor(v1, off);
        v2 += __shfl_xor(v2, off);
    }
    if (lane == 0) {
        ws[WS_S1 + wid] = v1;
        ws[WS_S2 + wid] = v2;
    }

    // ---- finish adj pack (no barrier dependency) ----
    unsigned int bits = 0;
#pragma unroll
    for (int k = 0; k < 8; ++k) {
        bits |= (pv[k].x != 0 ? 1u : 0u) << (4 * k);
        bits |= (pv[k].y != 0 ? 1u : 0u) << (4 * k + 1);
        bits |= (pv[k].z != 0 ? 1u : 0u) << (4 * k + 2);
        bits |= (pv[k].w != 0 ? 1u : 0u) << (4 * k + 3);
    }
    ((unsigned int*)(ws + WS_ABITS))[(size_t)prow * 128 + pword] = bits;

    __syncthreads();
    // transpose 4 rows x 64 f -> WhT bf16 [b][f][n0..n0+3]
    if (threadIdx.x < 64) {
        int f = threadIdx.x;
        int wid0 = blockIdx.x * 4;
        int b  = wid0 >> 12;         // wid0 / NN
        int n0 = wid0 & (NN - 1);
        unsigned short* whT = (unsigned short*)(ws + WS_WHT);
        uint2 pk;
        pk.x = pack2bf(tbuf[0][f], tbuf[1][f]);
        pk.y = pack2bf(tbuf[2][f], tbuf[3][f]);
        *(uint2*)&whT[(size_t)(b * FOUT + f) * NN + n0] = pk;
    }
}

// K3: fused masked softmax + P@Wh via MFMA + in-block 16-wave reduction +
// softmax-divide + ELU -> final output. Adjacency from the 2 MiB bitmask:
// each lane hoists its full 256-j mask slice (2x int4) before the main loop.
// Block = 1024 threads = 16 waves; block = one 16-row tile x all 4096 j.
__global__ __launch_bounds__(1024, 4) void k3_attn(const float* __restrict__ ws,
                                                   float* __restrict__ out) {
    __shared__ float red[16][2048];   // 128 KiB: per-wave D-tile partials
    __shared__ float lred[16][32];    // 2 KiB: per-wave l partials (b*16+row)
    const int tid  = threadIdx.x;
    const int w    = tid >> 6;                   // wave id = j-chunk 0..15
    const int lane = tid & 63;
    const int col  = lane & 15;
    const int quad = lane >> 4;
    const int rt   = blockIdx.x;                 // row-tile 0..255
    const int i0   = rt * 16;
    const int jbase = w * 256;

    const float* __restrict__ s1 = ws + WS_S1;
    const float* __restrict__ s2 = ws + WS_S2;
    const unsigned short* __restrict__ whT = (const unsigned short*)(ws + WS_WHT);
    const unsigned int* __restrict__ abits = (const unsigned int*)(ws + WS_ABITS);

    // hoist this lane's whole mask slice: row i0+col, words [w*8, w*8+8)
    unsigned int mrow[8];
    {
        const int4* mp = (const int4*)&abits[(size_t)(i0 + col) * 128 + w * 8];
        *(int4*)&mrow[0] = mp[0];
        *(int4*)&mrow[4] = mp[1];
    }

    float s1a[2];
#pragma unroll
    for (int b = 0; b < 2; ++b) s1a[b] = s1[b * NN + i0 + col];

    f32x4 acc[2][4];        // [batch][nt]
    float lsum[2] = {0.f, 0.f};
#pragma unroll
    for (int b = 0; b < 2; ++b)
#pragma unroll
        for (int nt = 0; nt < 4; ++nt) acc[b][nt] = (f32x4)0.f;

#pragma unroll
    for (int ks = 0; ks < 8; ++ks) {
        const int j8 = jbase + ks * 32 + quad * 8;   // this lane's 8-j base
        const unsigned int mb = (mrow[ks] >> (quad * 8)) & 0xffu;
#pragma unroll
        for (int b = 0; b < 2; ++b) {
            float4 s2lo = *(const float4*)&s2[b * NN + j8];
            float4 s2hi = *(const float4*)&s2[b * NN + j8 + 4];
            float sj[8] = {s2lo.x, s2lo.y, s2lo.z, s2lo.w,
                           s2hi.x, s2hi.y, s2hi.z, s2hi.w};
            float p[8];
#pragma unroll
            for (int jj = 0; jj < 8; ++jj) {
                float e = s1a[b] + sj[jj];
                e = fmaxf(e, LALPHA * e);              // leakyrelu
                float pe = __expf(e);
                p[jj] = ((mb >> jj) & 1u) ? pe : 0.f;  // mask
                lsum[b] += p[jj];
            }
            unsigned int pk[4];
#pragma unroll
            for (int q = 0; q < 4; ++q) pk[q] = pack2bf(p[2 * q], p[2 * q + 1]);
            short8 afrag = *(short8*)pk;
#pragma unroll
            for (int nt = 0; nt < 4; ++nt) {
                short8 bfrag = *(const short8*)
                    &whT[(size_t)(b * FOUT + nt * 16 + col) * NN + j8];
                acc[b][nt] = __builtin_amdgcn_mfma_f32_16x16x32_bf16(
                    afrag, bfrag, acc[b][nt], 0, 0, 0);
            }
        }
    }

    // ---- epilogue: LDS partials, 16-way in-block reduce, finalize ----
#pragma unroll
    for (int b = 0; b < 2; ++b) {
        // l: sum over quads -> row (=col) total for this wave's j-chunk
        float v = lsum[b];
        v += __shfl_xor(v, 16);
        v += __shfl_xor(v, 32);
        if (quad == 0) lred[w][b * 16 + col] = v;
#pragma unroll
        for (int nt = 0; nt < 4; ++nt)
#pragma unroll
            for (int reg = 0; reg < 4; ++reg)
                red[w][(((b * 4 + nt) * 4 + reg) << 6) + lane] = acc[b][nt][reg];
    }
    __syncthreads();

    // 2048 outputs per block, 1024 threads -> 2 each.
#pragma unroll
    for (int e = 0; e < 2; ++e) {
        int flat = e * 1024 + tid;                // b*1024 + r16*64 + f
        int f    = flat & 63;
        int r16  = (flat >> 6) & 15;
        int b    = flat >> 10;
        int q2   = r16 >> 2, reg = r16 & 3;
        int c2   = f & 15,   nt  = f >> 4;
        int ln   = q2 * 16 + c2;
        int off  = (((b * 4 + nt) * 4 + reg) << 6) + ln;
        float acv = 0.f, l = 0.f;
#pragma unroll
        for (int ww = 0; ww < 16; ++ww) {
            acv += red[ww][off];
            l   += lred[ww][b * 16 + r16];
        }
        float v = acv / l;
        out[(size_t)(((b * NN) + i0 + r16) << 6) + f] = v > 0.f ? v : (__expf(v) - 1.f);
    }
}

extern "C" void kernel_launch(void* const* d_in, const int* in_sizes, int n_in,
                              void* d_out, int out_size, void* d_ws, size_t ws_size,
                              hipStream_t stream) {
    const float* h   = (const float*)d_in[0];
    const int*   adj = (const int*)d_in[1];
    const float* W   = (const float*)d_in[2];
    const float* a   = (const float*)d_in[3];
    float* ws  = (float*)d_ws;
    float* out = (float*)d_out;

    hipLaunchKernelGGL(k1_proj, dim3(NB * NN / 4), dim3(256), 0, stream, h, W, a, adj, ws);
    hipLaunchKernelGGL(k3_attn, dim3(256), dim3(1024), 0, stream, ws, out);
}

// Round 3
// 148.620 us; speedup vs baseline: 1.0121x; 1.0092x over previous
//
#include <hip/hip_runtime.h>
#include <hip/hip_bf16.h>
#include <math.h>

#define NB 2
#define NN 4096
#define FIN 128
#define FOUT 64
#define LALPHA 0.2f

// ws float-offsets
#define WS_S1    0                          // NB*NN floats (pre-scaled by log2e)
#define WS_S2    (NB*NN)                    // NB*NN floats (pre-scaled by log2e)
#define WS_WHT   (2*NB*NN)                  // NB*FOUT*NN ushorts = NB*FOUT*NN/2 floats
#define WS_ABITS (WS_WHT + NB*FOUT*NN/2)    // NN*(NN/32) uint32 = 2 MiB

typedef __attribute__((ext_vector_type(8))) short short8;
typedef __attribute__((ext_vector_type(4))) float f32x4;

static __device__ inline unsigned int pack2bf(float x, float y) {
    float2 f2; f2.x = x; f2.y = y;
    __hip_bfloat162 pp = __float22bfloat162_rn(f2);
    return *reinterpret_cast<unsigned int*>(&pp);
}

// K1: Wh = h@W ; s1 = log2e*(Wh@a1) ; s2 = log2e*(Wh@a2) ; WhT bf16 [b][f][j].
// One wave per (b,row); lane = out feature. Block = 4 waves = 4 consecutive rows.
// ALSO: packs 2 rows of adj into the 2 MiB bitmask (independent streaming work
// that overlaps the shfl/fma latency chain of the projection).
__global__ __launch_bounds__(256) void k1_proj(const float* __restrict__ h,
                                               const float* __restrict__ W,
                                               const float* __restrict__ a,
                                               const int* __restrict__ adj,
                                               float* __restrict__ ws) {
    __shared__ float tbuf[4][68];
    int gid  = blockIdx.x * 256 + threadIdx.x;
    int wid  = gid >> 6;            // 0 .. NB*NN-1
    int lane = threadIdx.x & 63;
    int w    = threadIdx.x >> 6;

    // ---- adj pack: issue loads early (independent of proj chain) ----
    int prow  = 2 * blockIdx.x + (threadIdx.x >> 7);
    int pword = threadIdx.x & 127;
    const int4* psrc = (const int4*)&adj[(size_t)prow * NN + pword * 32];
    int4 pv[8];
#pragma unroll
    for (int k = 0; k < 8; ++k) pv[k] = psrc[k];

    // ---- projection ----
    const float* hrow = h + (size_t)wid * FIN;
    float h0 = hrow[lane];
    float h1 = hrow[64 + lane];
    float acc = 0.f;
#pragma unroll
    for (int f = 0; f < 64; ++f) {
        float hf = __shfl(h0, f);
        acc = fmaf(hf, W[f * FOUT + lane], acc);
    }
#pragma unroll
    for (int f = 0; f < 64; ++f) {
        float hf = __shfl(h1, f);
        acc = fmaf(hf, W[(64 + f) * FOUT + lane], acc);
    }
    tbuf[w][lane] = acc;
    float v1 = acc * a[lane];
    float v2 = acc * a[FOUT + lane];
#pragma unroll
    for (int off = 32; off; off >>= 1) {
        v1 += __shfl_xor(v1, off);
        v2 += __shfl_xor(v2, off);
    }
    if (lane == 0) {
        ws[WS_S1 + wid] = v1 * 1.44269504088896f;   // pre-scale for exp2 in k3
        ws[WS_S2 + wid] = v2 * 1.44269504088896f;
    }

    // ---- finish adj pack (no barrier dependency) ----
    unsigned int bits = 0;
#pragma unroll
    for (int k = 0; k < 8; ++k) {
        bits |= (pv[k].x != 0 ? 1u : 0u) << (4 * k);
        bits |= (pv[k].y != 0 ? 1u : 0u) << (4 * k + 1);
        bits |= (pv[k].z != 0 ? 1u : 0u) << (4 * k + 2);
        bits |= (pv[k].w != 0 ? 1u : 0u) << (4 * k + 3);
    }
    ((unsigned int*)(ws + WS_ABITS))[(size_t)prow * 128 + pword] = bits;

    __syncthreads();
    // transpose 4 rows x 64 f -> WhT bf16 [b][f][n0..n0+3]
    if (threadIdx.x < 64) {
        int f = threadIdx.x;
        int wid0 = blockIdx.x * 4;
        int b  = wid0 >> 12;         // wid0 / NN
        int n0 = wid0 & (NN - 1);
        unsigned short* whT = (unsigned short*)(ws + WS_WHT);
        uint2 pk;
        pk.x = pack2bf(tbuf[0][f], tbuf[1][f]);
        pk.y = pack2bf(tbuf[2][f], tbuf[3][f]);
        *(uint2*)&whT[(size_t)(b * FOUT + f) * NN + n0] = pk;
    }
}

// K3: fused masked softmax + P@Wh via MFMA + in-block tree reduction +
// softmax-divide + ELU -> final output.
// Split by batch: grid = 512 blocks (rt 0..255, b 0..1); block = 16 waves,
// one batch, one 16-row tile x all 4096 j. Wave w covers j [w*256,(w+1)*256).
// LDS 33 KB (tree reduce) -> 2 blocks/CU = 32 waves/CU (2x TLP vs r1).
__global__ __launch_bounds__(1024, 8) void k3_attn(const float* __restrict__ ws,
                                                   float* __restrict__ out) {
    __shared__ float red[8][1024];    // 32 KiB tree-reduction buffer
    __shared__ float lred[16][16];    // 1 KiB l partials
    const int tid  = threadIdx.x;
    const int w    = tid >> 6;                   // wave id = j-chunk 0..15
    const int lane = tid & 63;
    const int col  = lane & 15;
    const int quad = lane >> 4;
    const int rt   = blockIdx.x & 255;           // row-tile 0..255
    const int b    = blockIdx.x >> 8;            // batch
    const int i0   = rt * 16;
    const int jbase = w * 256;

    const float* __restrict__ s1 = ws + WS_S1 + b * NN;
    const float* __restrict__ s2 = ws + WS_S2 + b * NN;
    const unsigned short* __restrict__ whT =
        (const unsigned short*)(ws + WS_WHT) + (size_t)b * FOUT * NN;
    const unsigned int* __restrict__ abits = (const unsigned int*)(ws + WS_ABITS);

    // hoist this lane's whole mask slice: row i0+col, words [w*8, w*8+8)
    unsigned int mrow[8];
    {
        const int4* mp = (const int4*)&abits[(size_t)(i0 + col) * 128 + w * 8];
        *(int4*)&mrow[0] = mp[0];
        *(int4*)&mrow[4] = mp[1];
    }

    float s1a = s1[i0 + col];
    f32x4 acc[4];
    float lsum = 0.f;
#pragma unroll
    for (int nt = 0; nt < 4; ++nt) acc[nt] = (f32x4)0.f;

#pragma unroll
    for (int ks = 0; ks < 8; ++ks) {
        const int j8 = jbase + ks * 32 + quad * 8;   // this lane's 8-j base
        const unsigned int mb = (mrow[ks] >> (quad * 8)) & 0xffu;
        float4 s2lo = *(const float4*)&s2[j8];
        float4 s2hi = *(const float4*)&s2[j8 + 4];
        float sj[8] = {s2lo.x, s2lo.y, s2lo.z, s2lo.w,
                       s2hi.x, s2hi.y, s2hi.z, s2hi.w};
        float p[8];
#pragma unroll
        for (int jj = 0; jj < 8; ++jj) {
            float e = s1a + sj[jj];
            e = fmaxf(e, LALPHA * e);              // leakyrelu (commutes w/ log2e scale)
            float pe = exp2f(e);                   // exp(e/log2e) == 2^e
            p[jj] = ((mb >> jj) & 1u) ? pe : 0.f;  // mask
            lsum += p[jj];
        }
        unsigned int pk[4];
#pragma unroll
        for (int q = 0; q < 4; ++q) pk[q] = pack2bf(p[2 * q], p[2 * q + 1]);
        short8 afrag = *(short8*)pk;
#pragma unroll
        for (int nt = 0; nt < 4; ++nt) {
            short8 bfrag = *(const short8*)
                &whT[(size_t)(nt * 16 + col) * NN + j8];
            acc[nt] = __builtin_amdgcn_mfma_f32_16x16x32_bf16(
                afrag, bfrag, acc[nt], 0, 0, 0);
        }
    }

    // ---- epilogue: l partials, 4-stage tree reduce, finalize in wave 0 ----
    {
        float v = lsum;
        v += __shfl_xor(v, 16);
        v += __shfl_xor(v, 32);
        if (quad == 0) lred[w][col] = v;
    }
#pragma unroll
    for (int half = 8; half >= 1; half >>= 1) {
        __syncthreads();                           // WAR vs previous stage reads
        if (w >= half && w < 2 * half) {
#pragma unroll
            for (int nt = 0; nt < 4; ++nt)
#pragma unroll
                for (int reg = 0; reg < 4; ++reg)
                    red[w - half][((nt * 4 + reg) << 6) + lane] = acc[nt][reg];
        }
        __syncthreads();
        if (w < half) {
#pragma unroll
            for (int nt = 0; nt < 4; ++nt)
#pragma unroll
                for (int reg = 0; reg < 4; ++reg)
                    acc[nt][reg] += red[w][((nt * 4 + reg) << 6) + lane];
        }
    }

    if (w == 0) {
        // l totals for this lane's 4 output rows (r16 = quad*4 + reg)
        float lv[4];
#pragma unroll
        for (int reg = 0; reg < 4; ++reg) {
            float s = 0.f;
#pragma unroll
            for (int ww = 0; ww < 16; ++ww) s += lred[ww][quad * 4 + reg];
            lv[reg] = s;
        }
#pragma unroll
        for (int nt = 0; nt < 4; ++nt)
#pragma unroll
            for (int reg = 0; reg < 4; ++reg) {
                float v = acc[nt][reg] / lv[reg];
                v = v > 0.f ? v : (__expf(v) - 1.f);   // elu (natural exp)
                out[((size_t)(b * NN + i0 + quad * 4 + reg) << 6) + nt * 16 + col] = v;
            }
    }
}

extern "C" void kernel_launch(void* const* d_in, const int* in_sizes, int n_in,
                              void* d_out, int out_size, void* d_ws, size_t ws_size,
                              hipStream_t stream) {
    const float* h   = (const float*)d_in[0];
    const int*   adj = (const int*)d_in[1];
    const float* W   = (const float*)d_in[2];
    const float* a   = (const float*)d_in[3];
    float* ws  = (float*)d_ws;
    float* out = (float*)d_out;

    hipLaunchKernelGGL(k1_proj, dim3(NB * NN / 4), dim3(256), 0, stream, h, W, a, adj, ws);
    hipLaunchKernelGGL(k3_attn, dim3(2 * 256), dim3(1024), 0, stream, ws, out);
}

// Round 4
// 144.573 us; speedup vs baseline: 1.0405x; 1.0280x over previous
//
#include <hip/hip_runtime.h>
#include <hip/hip_bf16.h>
#include <math.h>

#define NB 2
#define NN 4096
#define FIN 128
#define FOUT 64
#define LALPHA 0.2f

// ws float-offsets
#define WS_S1    0                          // NB*NN floats (pre-scaled by log2e)
#define WS_S2    (NB*NN)                    // NB*NN floats (pre-scaled by log2e)
#define WS_WHT   (2*NB*NN)                  // NB*FOUT*NN bf16, tile-major layout
#define WS_ABITS (WS_WHT + NB*FOUT*NN/2)    // NN*(NN/32) uint32 = 2 MiB

// whT tile-major layout: element (b, f, j) lives at
//   (b*(NN/32) + (j>>5)) * 2048 + f*32 + (j&31)
// so a wave's 16f x 8j bfrag load (lane = quad*16+col) is 1KB fully contiguous.

typedef __attribute__((ext_vector_type(8))) short short8;
typedef __attribute__((ext_vector_type(4))) float f32x4;

static __device__ inline unsigned int pack2bf(float x, float y) {
    float2 f2; f2.x = x; f2.y = y;
    __hip_bfloat162 pp = __float22bfloat162_rn(f2);
    return *reinterpret_cast<unsigned int*>(&pp);
}

// K1: Wh = h@W ; s1 = log2e*(Wh@a1) ; s2 = log2e*(Wh@a2) ; WhT bf16 tile-major.
// One wave per (b,row); lane = out feature. Block = 4 waves = 4 consecutive rows.
// ALSO packs 2 rows of adj into the 2 MiB bitmask (overlaps the proj chain).
__global__ __launch_bounds__(256) void k1_proj(const float* __restrict__ h,
                                               const float* __restrict__ W,
                                               const float* __restrict__ a,
                                               const int* __restrict__ adj,
                                               float* __restrict__ ws) {
    __shared__ float tbuf[4][68];
    int gid  = blockIdx.x * 256 + threadIdx.x;
    int wid  = gid >> 6;            // 0 .. NB*NN-1
    int lane = threadIdx.x & 63;
    int w    = threadIdx.x >> 6;

    // ---- adj pack: issue loads early (independent of proj chain) ----
    int prow  = 2 * blockIdx.x + (threadIdx.x >> 7);
    int pword = threadIdx.x & 127;
    const int4* psrc = (const int4*)&adj[(size_t)prow * NN + pword * 32];
    int4 pv[8];
#pragma unroll
    for (int k = 0; k < 8; ++k) pv[k] = psrc[k];

    // ---- projection ----
    const float* hrow = h + (size_t)wid * FIN;
    float h0 = hrow[lane];
    float h1 = hrow[64 + lane];
    float acc = 0.f;
#pragma unroll
    for (int f = 0; f < 64; ++f) {
        float hf = __shfl(h0, f);
        acc = fmaf(hf, W[f * FOUT + lane], acc);
    }
#pragma unroll
    for (int f = 0; f < 64; ++f) {
        float hf = __shfl(h1, f);
        acc = fmaf(hf, W[(64 + f) * FOUT + lane], acc);
    }
    tbuf[w][lane] = acc;
    float v1 = acc * a[lane];
    float v2 = acc * a[FOUT + lane];
#pragma unroll
    for (int off = 32; off; off >>= 1) {
        v1 += __shfl_xor(v1, off);
        v2 += __shfl_xor(v2, off);
    }
    if (lane == 0) {
        ws[WS_S1 + wid] = v1 * 1.44269504088896f;   // pre-scale for exp2 in k3
        ws[WS_S2 + wid] = v2 * 1.44269504088896f;
    }

    // ---- finish adj pack (no barrier dependency) ----
    unsigned int bits = 0;
#pragma unroll
    for (int k = 0; k < 8; ++k) {
        bits |= (pv[k].x != 0 ? 1u : 0u) << (4 * k);
        bits |= (pv[k].y != 0 ? 1u : 0u) << (4 * k + 1);
        bits |= (pv[k].z != 0 ? 1u : 0u) << (4 * k + 2);
        bits |= (pv[k].w != 0 ? 1u : 0u) << (4 * k + 3);
    }
    ((unsigned int*)(ws + WS_ABITS))[(size_t)prow * 128 + pword] = bits;

    __syncthreads();
    // transpose 4 rows x 64 f -> tile-major whT
    if (threadIdx.x < 64) {
        int f = threadIdx.x;
        int wid0 = blockIdx.x * 4;
        int b  = wid0 >> 12;         // wid0 / NN
        int n0 = wid0 & (NN - 1);
        unsigned short* whT = (unsigned short*)(ws + WS_WHT);
        uint2 pk;
        pk.x = pack2bf(tbuf[0][f], tbuf[1][f]);
        pk.y = pack2bf(tbuf[2][f], tbuf[3][f]);
        size_t off = ((size_t)(b * 128 + (n0 >> 5)) * 2048) + f * 32 + (n0 & 31);
        *(uint2*)&whT[off] = pk;
    }
}

// K3: fused masked softmax + P@Wh via MFMA + flat in-block reduction + ELU.
// Grid = 256 blocks (rt 0..127 x b 0..1); block = 16 waves, 32 rows
// (2 row-groups of 16), all 4096 j. Wave w covers j [w*256,(w+1)*256).
// bfrag (whT) loads are 1KB coalesced and SHARED by both row-groups.
__global__ __launch_bounds__(1024, 4) void k3_attn(const float* __restrict__ ws,
                                                   float* __restrict__ out) {
    __shared__ float red[16][2048];   // 128 KiB: per-wave partials (2 groups)
    __shared__ float lred[16][32];    // 2 KiB: l partials (g*16+row)
    const int tid  = threadIdx.x;
    const int w    = tid >> 6;                   // wave id = j-chunk 0..15
    const int lane = tid & 63;
    const int col  = lane & 15;
    const int quad = lane >> 4;
    const int rt   = blockIdx.x & 127;           // 32-row tile 0..127
    const int b    = blockIdx.x >> 7;            // batch
    const int i0   = rt * 32;
    const int jbase = w * 256;

    const float* __restrict__ s1 = ws + WS_S1 + b * NN;
    const float* __restrict__ s2 = ws + WS_S2 + b * NN;
    const unsigned short* __restrict__ whT =
        (const unsigned short*)(ws + WS_WHT) + (size_t)b * FOUT * NN;
    const unsigned int* __restrict__ abits = (const unsigned int*)(ws + WS_ABITS);

    // hoist mask slices: rows i0+g*16+col, words [w*8, w*8+8)
    unsigned int mrow[2][8];
#pragma unroll
    for (int g = 0; g < 2; ++g) {
        const int4* mp = (const int4*)&abits[(size_t)(i0 + g * 16 + col) * 128 + w * 8];
        *(int4*)&mrow[g][0] = mp[0];
        *(int4*)&mrow[g][4] = mp[1];
    }

    float s1a[2];
#pragma unroll
    for (int g = 0; g < 2; ++g) s1a[g] = s1[i0 + g * 16 + col];

    f32x4 acc[2][4];          // [group][nt]
    float lsum[2] = {0.f, 0.f};
#pragma unroll
    for (int g = 0; g < 2; ++g)
#pragma unroll
        for (int nt = 0; nt < 4; ++nt) acc[g][nt] = (f32x4)0.f;

#pragma unroll
    for (int ks = 0; ks < 8; ++ks) {
        const int j8 = jbase + ks * 32 + quad * 8;   // this lane's 8-j base
        // coalesced 1KB bfrag loads, shared by both row-groups
        const unsigned short* wb = whT + (size_t)(w * 8 + ks) * 2048;
        short8 bf[4];
#pragma unroll
        for (int nt = 0; nt < 4; ++nt)
            bf[nt] = *(const short8*)&wb[nt * 512 + col * 32 + quad * 8];

        float4 s2lo = *(const float4*)&s2[j8];
        float4 s2hi = *(const float4*)&s2[j8 + 4];
        float sj[8] = {s2lo.x, s2lo.y, s2lo.z, s2lo.w,
                       s2hi.x, s2hi.y, s2hi.z, s2hi.w};
#pragma unroll
        for (int g = 0; g < 2; ++g) {
            const unsigned int mb = (mrow[g][ks] >> (quad * 8)) & 0xffu;
            float p[8];
#pragma unroll
            for (int jj = 0; jj < 8; ++jj) {
                float e = s1a[g] + sj[jj];
                e = fmaxf(e, LALPHA * e);              // leakyrelu
                float pe = exp2f(e);                   // inputs pre-scaled by log2e
                p[jj] = ((mb >> jj) & 1u) ? pe : 0.f;  // mask
                lsum[g] += p[jj];
            }
            unsigned int pk[4];
#pragma unroll
            for (int q = 0; q < 4; ++q) pk[q] = pack2bf(p[2 * q], p[2 * q + 1]);
            short8 afrag = *(short8*)pk;
#pragma unroll
            for (int nt = 0; nt < 4; ++nt)
                acc[g][nt] = __builtin_amdgcn_mfma_f32_16x16x32_bf16(
                    afrag, bf[nt], acc[g][nt], 0, 0, 0);
        }
    }

    // ---- epilogue: flat LDS partials, one barrier, 16-way reduce ----
#pragma unroll
    for (int g = 0; g < 2; ++g) {
        float v = lsum[g];
        v += __shfl_xor(v, 16);
        v += __shfl_xor(v, 32);
        if (quad == 0) lred[w][g * 16 + col] = v;
#pragma unroll
        for (int nt = 0; nt < 4; ++nt)
#pragma unroll
            for (int reg = 0; reg < 4; ++reg)
                red[w][g * 1024 + ((nt * 4 + reg) << 6) + lane] = acc[g][nt][reg];
    }
    __syncthreads();

    // 2048 outputs per block (32 rows x 64 f), 1024 threads -> 2 each.
#pragma unroll
    for (int e = 0; e < 2; ++e) {
        int flat = e * 1024 + tid;                // r32*64 + f
        int f    = flat & 63;
        int r32  = flat >> 6;                     // 0..31
        int g    = r32 >> 4;
        int r16  = r32 & 15;
        int q2   = r16 >> 2, reg = r16 & 3;
        int c2   = f & 15,   nt  = f >> 4;
        int ln   = q2 * 16 + c2;
        int off  = g * 1024 + ((nt * 4 + reg) << 6) + ln;
        float acv = 0.f, l = 0.f;
#pragma unroll
        for (int ww = 0; ww < 16; ++ww) {
            acv += red[ww][off];
            l   += lred[ww][g * 16 + r16];
        }
        float v = acv / l;
        out[((size_t)(b * NN + i0 + r32) << 6) + f] = v > 0.f ? v : (__expf(v) - 1.f);
    }
}

extern "C" void kernel_launch(void* const* d_in, const int* in_sizes, int n_in,
                              void* d_out, int out_size, void* d_ws, size_t ws_size,
                              hipStream_t stream) {
    const float* h   = (const float*)d_in[0];
    const int*   adj = (const int*)d_in[1];
    const float* W   = (const float*)d_in[2];
    const float* a   = (const float*)d_in[3];
    float* ws  = (float*)d_ws;
    float* out = (float*)d_out;

    hipLaunchKernelGGL(k1_proj, dim3(NB * NN / 4), dim3(256), 0, stream, h, W, a, adj, ws);
    hipLaunchKernelGGL(k3_attn, dim3(256), dim3(1024), 0, stream, ws, out);
}

// Round 5
// 140.037 us; speedup vs baseline: 1.0742x; 1.0324x over previous
//
#include <hip/hip_runtime.h>
#include <hip/hip_bf16.h>
#include <math.h>

#define NB 2
#define NN 4096
#define FIN 128
#define FOUT 64
#define LALPHA 0.2f

// ws float-offsets
#define WS_S1    0                          // NB*NN floats (pre-scaled by log2e)
#define WS_S2    (NB*NN)                    // NB*NN floats (pre-scaled by log2e)
#define WS_WHT   (2*NB*NN)                  // NB*FOUT*NN bf16, tile-major layout
#define WS_ABITS (WS_WHT + NB*FOUT*NN/2)    // NN*(NN/32) uint32 = 2 MiB

// whT tile-major layout: element (b, f, j) lives at
//   (b*(NN/32) + (j>>5)) * 2048 + f*32 + (j&31)

typedef __attribute__((ext_vector_type(8))) short short8;
typedef __attribute__((ext_vector_type(4))) float f32x4;

static __device__ inline unsigned int pack2bf(float x, float y) {
    float2 f2; f2.x = x; f2.y = y;
    __hip_bfloat162 pp = __float22bfloat162_rn(f2);
    return *reinterpret_cast<unsigned int*>(&pp);
}

// async global->LDS, 16B per lane, dst = wave-uniform base + lane*16
#define GLL16(gsrc, ldst)                                                        \
    __builtin_amdgcn_global_load_lds(                                            \
        (const __attribute__((address_space(1))) void*)(gsrc),                   \
        (__attribute__((address_space(3))) void*)(ldst), 16, 0, 0)

// K1: Wh = h@W ; s1 = log2e*(Wh@a1) ; s2 = log2e*(Wh@a2) ; WhT bf16 tile-major.
// One wave per (b,row); lane = out feature. Block = 4 waves = 4 consecutive rows.
// ALSO packs 2 rows of adj into the 2 MiB bitmask (overlaps the proj chain).
__global__ __launch_bounds__(256) void k1_proj(const float* __restrict__ h,
                                               const float* __restrict__ W,
                                               const float* __restrict__ a,
                                               const int* __restrict__ adj,
                                               float* __restrict__ ws) {
    __shared__ float tbuf[4][68];
    int gid  = blockIdx.x * 256 + threadIdx.x;
    int wid  = gid >> 6;            // 0 .. NB*NN-1
    int lane = threadIdx.x & 63;
    int w    = threadIdx.x >> 6;

    // ---- adj pack: issue loads early (independent of proj chain) ----
    int prow  = 2 * blockIdx.x + (threadIdx.x >> 7);
    int pword = threadIdx.x & 127;
    const int4* psrc = (const int4*)&adj[(size_t)prow * NN + pword * 32];
    int4 pv[8];
#pragma unroll
    for (int k = 0; k < 8; ++k) pv[k] = psrc[k];

    // ---- projection ----
    const float* hrow = h + (size_t)wid * FIN;
    float h0 = hrow[lane];
    float h1 = hrow[64 + lane];
    float acc = 0.f;
#pragma unroll
    for (int f = 0; f < 64; ++f) {
        float hf = __shfl(h0, f);
        acc = fmaf(hf, W[f * FOUT + lane], acc);
    }
#pragma unroll
    for (int f = 0; f < 64; ++f) {
        float hf = __shfl(h1, f);
        acc = fmaf(hf, W[(64 + f) * FOUT + lane], acc);
    }
    tbuf[w][lane] = acc;
    float v1 = acc * a[lane];
    float v2 = acc * a[FOUT + lane];
#pragma unroll
    for (int off = 32; off; off >>= 1) {
        v1 += __shfl_xor(v1, off);
        v2 += __shfl_xor(v2, off);
    }
    if (lane == 0) {
        ws[WS_S1 + wid] = v1 * 1.44269504088896f;   // pre-scale for exp2 in k3
        ws[WS_S2 + wid] = v2 * 1.44269504088896f;
    }

    // ---- finish adj pack (no barrier dependency) ----
    unsigned int bits = 0;
#pragma unroll
    for (int k = 0; k < 8; ++k) {
        bits |= (pv[k].x != 0 ? 1u : 0u) << (4 * k);
        bits |= (pv[k].y != 0 ? 1u : 0u) << (4 * k + 1);
        bits |= (pv[k].z != 0 ? 1u : 0u) << (4 * k + 2);
        bits |= (pv[k].w != 0 ? 1u : 0u) << (4 * k + 3);
    }
    ((unsigned int*)(ws + WS_ABITS))[(size_t)prow * 128 + pword] = bits;

    __syncthreads();
    // transpose 4 rows x 64 f -> tile-major whT
    if (threadIdx.x < 64) {
        int f = threadIdx.x;
        int wid0 = blockIdx.x * 4;
        int b  = wid0 >> 12;         // wid0 / NN
        int n0 = wid0 & (NN - 1);
        unsigned short* whT = (unsigned short*)(ws + WS_WHT);
        uint2 pk;
        pk.x = pack2bf(tbuf[0][f], tbuf[1][f]);
        pk.y = pack2bf(tbuf[2][f], tbuf[3][f]);
        size_t off = ((size_t)(b * 128 + (n0 >> 5)) * 2048) + f * 32 + (n0 & 31);
        *(uint2*)&whT[off] = pk;
    }
}

// K3: fused masked softmax + P@Wh via MFMA + flat in-block reduction + ELU.
// Grid = 256 blocks (rt 0..127 x b 0..1); block = 16 waves, 32 rows, all j.
// Main loop: whT tiles staged via double-buffered global_load_lds into the
// wave's PRIVATE 8KB slot of the (otherwise idle) reduction LDS. Counted
// inline-asm vmcnt keeps 6 loads in flight across iterations; no barriers
// in the loop, so no compiler drain point exists.
__global__ __launch_bounds__(1024, 4) void k3_attn(const float* __restrict__ ws,
                                                   float* __restrict__ out) {
    __shared__ float redbuf[16 * 2048];   // 128 KiB: staging slots, then partials
    __shared__ float lred[16][32];        // 2 KiB: l partials (g*16+row)
    const int tid  = threadIdx.x;
    const int w    = tid >> 6;                   // wave id = j-chunk 0..15
    const int lane = tid & 63;
    const int col  = lane & 15;
    const int quad = lane >> 4;
    const int rt   = blockIdx.x & 127;           // 32-row tile 0..127
    const int b    = blockIdx.x >> 7;            // batch
    const int i0   = rt * 32;
    const int jbase = w * 256;

    const float* __restrict__ s1 = ws + WS_S1 + b * NN;
    const float* __restrict__ s2 = ws + WS_S2 + b * NN;
    const unsigned short* __restrict__ whT =
        (const unsigned short*)(ws + WS_WHT) + (size_t)b * FOUT * NN;
    const unsigned int* __restrict__ abits = (const unsigned int*)(ws + WS_ABITS);

    char* slot = (char*)redbuf + w * 8192;            // wave-private: 2 x 4KB bufs
    const unsigned short* wsrc = whT + (size_t)w * 8 * 2048;  // tile (w*8+ks) @ +ks*2048
    const int lsrc = col * 32 + quad * 8;             // per-lane src perm (shorts)

    // ---- prologue: masks + s1a, then full drain ----
    unsigned int mrow[2][8];
#pragma unroll
    for (int g = 0; g < 2; ++g) {
        const int4* mp = (const int4*)&abits[(size_t)(i0 + g * 16 + col) * 128 + w * 8];
        *(int4*)&mrow[g][0] = mp[0];
        *(int4*)&mrow[g][4] = mp[1];
    }
    float s1a[2];
#pragma unroll
    for (int g = 0; g < 2; ++g) s1a[g] = s1[i0 + g * 16 + col];
    asm volatile("s_waitcnt vmcnt(0)" ::: "memory");

    // ---- issue prefetch: s2+tile for ks=0 (buf0) and ks=1 (buf1) ----
    float4 s2lo[2], s2hi[2];
#define LOAD_S2(ks, sl)                                                   \
    do {                                                                  \
        s2lo[sl] = *(const float4*)&s2[jbase + (ks) * 32 + quad * 8];     \
        s2hi[sl] = *(const float4*)&s2[jbase + (ks) * 32 + quad * 8 + 4]; \
    } while (0)
#define ISSUE_TILE(ks, sl)                                                \
    do {                                                                  \
        const unsigned short* wb_ = wsrc + (size_t)(ks) * 2048;           \
        GLL16(wb_ + 0 * 512 + lsrc, slot + (sl) * 4096 + 0 * 1024);       \
        GLL16(wb_ + 1 * 512 + lsrc, slot + (sl) * 4096 + 1 * 1024);       \
        GLL16(wb_ + 2 * 512 + lsrc, slot + (sl) * 4096 + 2 * 1024);       \
        GLL16(wb_ + 3 * 512 + lsrc, slot + (sl) * 4096 + 3 * 1024);       \
    } while (0)

    LOAD_S2(0, 0); ISSUE_TILE(0, 0);
    LOAD_S2(1, 1); ISSUE_TILE(1, 1);

    f32x4 acc[2][4];          // [group][nt]
    float lsum[2] = {0.f, 0.f};
#pragma unroll
    for (int g = 0; g < 2; ++g)
#pragma unroll
        for (int nt = 0; nt < 4; ++nt) acc[g][nt] = (f32x4)0.f;

#pragma unroll
    for (int ks = 0; ks < 8; ++ks) {
        const int sl = ks & 1;
        // steady state: newest 6 outstanding = s2(ks+1)[2] + tile(ks+1)[4];
        // everything older (s2(ks), tile ks) complete. FIFO semantics.
        if (ks == 7) asm volatile("s_waitcnt vmcnt(0)" ::: "memory");
        else         asm volatile("s_waitcnt vmcnt(6)" ::: "memory");

        float sj[8] = {s2lo[sl].x, s2lo[sl].y, s2lo[sl].z, s2lo[sl].w,
                       s2hi[sl].x, s2hi[sl].y, s2hi[sl].z, s2hi[sl].w};
        short8 afrag[2];
#pragma unroll
        for (int g = 0; g < 2; ++g) {
            const unsigned int mb = (mrow[g][ks] >> (quad * 8)) & 0xffu;
            float p[8];
#pragma unroll
            for (int jj = 0; jj < 8; ++jj) {
                float e = s1a[g] + sj[jj];
                e = fmaxf(e, LALPHA * e);              // leakyrelu
                float pe = exp2f(e);                   // inputs pre-scaled by log2e
                p[jj] = ((mb >> jj) & 1u) ? pe : 0.f;  // mask
                lsum[g] += p[jj];
            }
            unsigned int pk[4];
#pragma unroll
            for (int q = 0; q < 4; ++q) pk[q] = pack2bf(p[2 * q], p[2 * q + 1]);
            afrag[g] = *(short8*)pk;
        }
#pragma unroll
        for (int nt = 0; nt < 4; ++nt) {
            short8 bf = *(const short8*)(slot + sl * 4096 + nt * 1024 + lane * 16);
            acc[0][nt] = __builtin_amdgcn_mfma_f32_16x16x32_bf16(
                afrag[0], bf, acc[0][nt], 0, 0, 0);
            acc[1][nt] = __builtin_amdgcn_mfma_f32_16x16x32_bf16(
                afrag[1], bf, acc[1][nt], 0, 0, 0);
        }
        if (ks < 6) { LOAD_S2(ks + 2, sl); ISSUE_TILE(ks + 2, sl); }
    }

    // ---- epilogue: flat LDS partials (reuse staging slots), one barrier ----
    float* red_w = redbuf + w * 2048;
#pragma unroll
    for (int g = 0; g < 2; ++g) {
        float v = lsum[g];
        v += __shfl_xor(v, 16);
        v += __shfl_xor(v, 32);
        if (quad == 0) lred[w][g * 16 + col] = v;
#pragma unroll
        for (int nt = 0; nt < 4; ++nt)
#pragma unroll
            for (int reg = 0; reg < 4; ++reg)
                red_w[g * 1024 + ((nt * 4 + reg) << 6) + lane] = acc[g][nt][reg];
    }
    __syncthreads();

    // 2048 outputs per block (32 rows x 64 f), 1024 threads -> 2 each.
#pragma unroll
    for (int e = 0; e < 2; ++e) {
        int flat = e * 1024 + tid;                // r32*64 + f
        int f    = flat & 63;
        int r32  = flat >> 6;                     // 0..31
        int g    = r32 >> 4;
        int r16  = r32 & 15;
        int q2   = r16 >> 2, reg = r16 & 3;
        int c2   = f & 15,   nt  = f >> 4;
        int ln   = q2 * 16 + c2;
        int off  = g * 1024 + ((nt * 4 + reg) << 6) + ln;
        float acv = 0.f, l = 0.f;
#pragma unroll
        for (int ww = 0; ww < 16; ++ww) {
            acv += redbuf[ww * 2048 + off];
            l   += lred[ww][g * 16 + r16];
        }
        float v = acv / l;
        out[((size_t)(b * NN + i0 + r32) << 6) + f] = v > 0.f ? v : (__expf(v) - 1.f);
    }
}

extern "C" void kernel_launch(void* const* d_in, const int* in_sizes, int n_in,
                              void* d_out, int out_size, void* d_ws, size_t ws_size,
                              hipStream_t stream) {
    const float* h   = (const float*)d_in[0];
    const int*   adj = (const int*)d_in[1];
    const float* W   = (const float*)d_in[2];
    const float* a   = (const float*)d_in[3];
    float* ws  = (float*)d_ws;
    float* out = (float*)d_out;

    hipLaunchKernelGGL(k1_proj, dim3(NB * NN / 4), dim3(256), 0, stream, h, W, a, adj, ws);
    hipLaunchKernelGGL(k3_attn, dim3(256), dim3(1024), 0, stream, ws, out);
}